// Round 1
// baseline (768.396 us; speedup 1.0000x reference)
//
#include <hip/hip_runtime.h>
#include <cstdint>
#include <cstddef>

#define N_NODES 100000
#define N_EDGES 1600000
#define D 128
#define NLAYERS 3

// ---------------- setup kernels ----------------

__global__ void count_deg_kernel(const int* __restrict__ col, int* __restrict__ deg, int e) {
    int i = blockIdx.x * 256 + threadIdx.x;
    if (i < e) atomicAdd(&deg[col[i]], 1);
}

__global__ void dinv_kernel(const int* __restrict__ deg, float* __restrict__ dinv, int n) {
    int i = blockIdx.x * 256 + threadIdx.x;
    if (i < n) dinv[i] = rsqrtf((float)(deg[i] + 1));  // +1 = self loop; always > 0
}

// exclusive scan, step 1: per-256-block exclusive scan + block sums
__global__ void scan1_kernel(const int* __restrict__ deg, int* __restrict__ excl,
                             int* __restrict__ bsums, int n) {
    __shared__ int tmp[256];
    int t = threadIdx.x;
    int g = blockIdx.x * 256 + t;
    int v = (g < n) ? deg[g] : 0;
    tmp[t] = v;
    __syncthreads();
    for (int off = 1; off < 256; off <<= 1) {
        int x = (t >= off) ? tmp[t - off] : 0;
        __syncthreads();
        tmp[t] += x;
        __syncthreads();
    }
    if (g < n) excl[g] = tmp[t] - v;              // exclusive within block
    if (t == 255) bsums[blockIdx.x] = tmp[255];   // block total
}

// step 2: single-block exclusive scan over block sums (nb <= 512)
__global__ void scan2_kernel(int* __restrict__ bsums, int nb) {
    __shared__ int tmp[512];
    int t = threadIdx.x;
    int v = (t < nb) ? bsums[t] : 0;
    tmp[t] = v;
    __syncthreads();
    for (int off = 1; off < 512; off <<= 1) {
        int x = (t >= off) ? tmp[t - off] : 0;
        __syncthreads();
        tmp[t] += x;
        __syncthreads();
    }
    if (t < nb) bsums[t] = tmp[t] - v;            // exclusive
}

// step 3: combine -> offsets, init cursors, write sentinel
__global__ void scan3_kernel(int* __restrict__ offsets, const int* __restrict__ bsums,
                             int* __restrict__ cursor, int n, int e) {
    int g = blockIdx.x * 256 + threadIdx.x;
    if (g < n) {
        int o = offsets[g] + bsums[g >> 8];
        offsets[g] = o;
        cursor[g] = o;
    }
    if (g == 0) offsets[n] = e;
}

__global__ void fill_csr_kernel(const int* __restrict__ row, const int* __restrict__ col,
                                const float* __restrict__ dinv, int* __restrict__ cursor,
                                int* __restrict__ src, float* __restrict__ w, int e) {
    int i = blockIdx.x * 256 + threadIdx.x;
    if (i < e) {
        int r = row[i], c = col[i];
        int pos = atomicAdd(&cursor[c], 1);
        src[pos] = r;
        w[pos] = dinv[r] * dinv[c];
    }
}

// ---------------- per-layer kernels ----------------

// One 64-thread block per node; each thread owns a float2 feature pair.
// acc = x[v]*dinv[v]^2 + sum_{incoming e} x[src_e]*w_e
__global__ void agg_kernel(const float* __restrict__ x, const int* __restrict__ offs,
                           const int* __restrict__ src, const float* __restrict__ w,
                           const float* __restrict__ dinv, float* __restrict__ out) {
    int v = blockIdx.x;
    int f = threadIdx.x;  // 0..63
    const float2* x2 = (const float2*)x;
    float dv = dinv[v];
    float2 xv = x2[(size_t)v * 64 + f];
    float ax = xv.x * dv * dv;
    float ay = xv.y * dv * dv;
    int i = offs[v], s1 = offs[v + 1];
    for (; i + 1 < s1; i += 2) {
        int sA = src[i], sB = src[i + 1];
        float wA = w[i], wB = w[i + 1];
        float2 xA = x2[(size_t)sA * 64 + f];
        float2 xB = x2[(size_t)sB * 64 + f];
        ax += xA.x * wA + xB.x * wB;
        ay += xA.y * wA + xB.y * wB;
    }
    if (i < s1) {
        int sA = src[i];
        float wA = w[i];
        float2 xA = x2[(size_t)sA * 64 + f];
        ax += xA.x * wA;
        ay += xA.y * wA;
    }
    float2 r;
    r.x = ax;
    r.y = ay;
    ((float2*)out)[(size_t)v * 64 + f] = r;
}

// out[M x 128] = relu(A[M x 128] @ W[128 x 128] + bias), 32 rows per block,
// W staged in LDS (64 KB), A-tile 16 KB, 4x4 register blocking.
__global__ __launch_bounds__(256, 2) void gemm_bias_relu_kernel(
    const float* __restrict__ A, const float* __restrict__ W,
    const float* __restrict__ bias, float* __restrict__ out, int M) {
    __shared__ float sW[128 * 128];  // 64 KB
    __shared__ float sX[32 * 128];   // 16 KB; reads are wave-broadcast, no pad needed
    int t = threadIdx.x;
    int tx = t & 31;   // 32 col-groups of 4
    int ty = t >> 5;   // 8 row-groups of 4
    int row0 = blockIdx.x * 32;

    const float4* W4 = (const float4*)W;
    float4* sW4 = (float4*)sW;
#pragma unroll
    for (int i = 0; i < 16; i++) sW4[t + 256 * i] = W4[t + 256 * i];

    const float4* A4 = (const float4*)A;
    float4* sX4 = (float4*)sX;
#pragma unroll
    for (int i = 0; i < 4; i++) {
        int c = t + 256 * i;
        int r = c >> 5, kc = c & 31;
        sX4[r * 32 + kc] = A4[(size_t)(row0 + r) * 32 + kc];
    }
    __syncthreads();

    float acc[4][4] = {};
#pragma unroll 8
    for (int k = 0; k < 128; k++) {
        float a0 = sX[(ty * 4 + 0) * 128 + k];
        float a1 = sX[(ty * 4 + 1) * 128 + k];
        float a2 = sX[(ty * 4 + 2) * 128 + k];
        float a3 = sX[(ty * 4 + 3) * 128 + k];
        float4 bv = *(const float4*)&sW[k * 128 + tx * 4];
        acc[0][0] += a0 * bv.x; acc[0][1] += a0 * bv.y; acc[0][2] += a0 * bv.z; acc[0][3] += a0 * bv.w;
        acc[1][0] += a1 * bv.x; acc[1][1] += a1 * bv.y; acc[1][2] += a1 * bv.z; acc[1][3] += a1 * bv.w;
        acc[2][0] += a2 * bv.x; acc[2][1] += a2 * bv.y; acc[2][2] += a2 * bv.z; acc[2][3] += a2 * bv.w;
        acc[3][0] += a3 * bv.x; acc[3][1] += a3 * bv.y; acc[3][2] += a3 * bv.z; acc[3][3] += a3 * bv.w;
    }

    float4 bb = ((const float4*)bias)[tx];
#pragma unroll
    for (int r = 0; r < 4; r++) {
        float4 o;
        o.x = fmaxf(acc[r][0] + bb.x, 0.0f);
        o.y = fmaxf(acc[r][1] + bb.y, 0.0f);
        o.z = fmaxf(acc[r][2] + bb.z, 0.0f);
        o.w = fmaxf(acc[r][3] + bb.w, 0.0f);
        ((float4*)out)[(size_t)(row0 + ty * 4 + r) * 32 + tx] = o;
    }
}

// ---------------- launch ----------------

extern "C" void kernel_launch(void* const* d_in, const int* in_sizes, int n_in,
                              void* d_out, int out_size, void* d_ws, size_t ws_size,
                              hipStream_t stream) {
    const int* edge = (const int*)d_in[0];   // [2, E] int32
    const float* emb = (const float*)d_in[1];
    const float* Ws = (const float*)d_in[2]; // [L, D, D]
    const float* bs = (const float*)d_in[3]; // [L, D]
    float* out = (float*)d_out;

    const int n = N_NODES, e = N_EDGES;
    const int* row = edge;       // sources
    const int* col = edge + e;   // targets

    char* p = (char*)d_ws;
    float* aggbuf = (float*)p;  p += (size_t)n * D * 4;       // 51.2 MB
    int* csr_src  = (int*)p;    p += (size_t)e * 4;           // 6.4 MB
    float* csr_w  = (float*)p;  p += (size_t)e * 4;           // 6.4 MB
    float* dinv   = (float*)p;  p += (size_t)n * 4;
    int* deg      = (int*)p;    p += (size_t)n * 4;
    int* offsets  = (int*)p;    p += (size_t)(n + 1) * 4;
    int* cursor   = (int*)p;    p += (size_t)n * 4;
    int* bsums    = (int*)p;    p += 4096;

    int nblk = (n + 255) / 256;   // 391
    int eblk = (e + 255) / 256;   // 6250

    hipMemsetAsync(deg, 0, (size_t)n * 4, stream);
    count_deg_kernel<<<eblk, 256, 0, stream>>>(col, deg, e);
    dinv_kernel<<<nblk, 256, 0, stream>>>(deg, dinv, n);
    scan1_kernel<<<nblk, 256, 0, stream>>>(deg, offsets, bsums, n);
    scan2_kernel<<<1, 512, 0, stream>>>(bsums, nblk);
    scan3_kernel<<<nblk, 256, 0, stream>>>(offsets, bsums, cursor, n, e);
    fill_csr_kernel<<<eblk, 256, 0, stream>>>(row, col, dinv, cursor, csr_src, csr_w, e);

    const float* x = emb;
    for (int l = 0; l < NLAYERS; l++) {
        agg_kernel<<<n, 64, 0, stream>>>(x, offsets, csr_src, csr_w, dinv, aggbuf);
        gemm_bias_relu_kernel<<<n / 32, 256, 0, stream>>>(
            aggbuf, Ws + (size_t)l * D * D, bs + (size_t)l * D, out, n);
        x = out;
    }
}